// Round 6
// baseline (259.590 us; speedup 1.0000x reference)
//
#include <hip/hip_runtime.h>

// ---------------------------------------------------------------------------
// TripletLossWithHardMining  (B=4096, D=1024, fp32 in, fp32 scalar out)
//
//  K1 row_stats : wave-per-row; combined per-row constants; d_ap, d_an_row;
//                 bf16 copies of a,p,n; init hard_n=0 / hard_p=+inf slots.
//  K2 gemm_mask : UNFUSED (grid.x=2 selects N or P), BK=64, A loaded
//                 DIRECTLY global->VGPR (MFMA A-layout == row-major 16B
//                 chunks; no LDS for A), B staged via global_load_lds(16B)
//                 with XOR chunk swizzle (slot = chunk ^ (row&7)).
//                 Epilogue in SQUARED-distance domain (monotone), masked row
//                 max/min reduced in-register, atomicMax/Min on uint bits.
//                 64 AGPR acc + ~32 VGPR A-frags -> 3 waves/SIMD.
//  K3 finalize  : hard = sqrt(selected sq); d_an/d_pp means; loss.
//
//  Dead-ends so far: R4 barrier-free per-wave vmcnt pipeline (184us, 15%
//  MfmaUtil); fused N+P (R3/R5) caps occupancy at 2 waves/SIMD via 128 AGPR.
// ---------------------------------------------------------------------------

#define NB 4096
#define DIM 1024
#define EPSF 1e-6f
#define D_EPS2 (1024.0f * 1e-6f * 1e-6f)

#define BM 128           // block tile (rows and cols)
#define BK 64            // k-tile (bf16 elems) -> 128 B rows, unpadded

typedef __bf16  bf16x8 __attribute__((ext_vector_type(8)));
typedef float   f32x4  __attribute__((ext_vector_type(4)));

__device__ __forceinline__ unsigned short f2bf(float x) {
    unsigned u = __float_as_uint(x);
    u += 0x7FFFu + ((u >> 16) & 1u);   // round-to-nearest-even
    return (unsigned short)(u >> 16);
}

// async 16B/lane global->LDS; lds base wave-uniform, data lands at base+lane*16
__device__ __forceinline__ void g2l16(const unsigned short* g, unsigned short* l) {
    __builtin_amdgcn_global_load_lds(
        (const __attribute__((address_space(1))) unsigned int*)g,
        (__attribute__((address_space(3))) unsigned int*)l, 16, 0, 0);
}

// stats layout (NB-float slots):
// 0: base_a[i] = |a_i|^2 + 2e*sum_a + D*e^2
// 1: cn[j]     = |n_j|^2 - 2e*sum_n
// 2: cp[j]     = |p_j|^2 - 2e*sum_p
// 3: d_ap   4: d_an_row   5: hard_n bits (sq)   6: hard_p bits (sq)

// wave-per-row: 1024 blocks x 4 waves; lane handles 4 float4 chunks per matrix
__global__ __launch_bounds__(256) void row_stats_kernel(
    const float* __restrict__ a, const float* __restrict__ p,
    const float* __restrict__ n,
    unsigned short* __restrict__ abf, unsigned short* __restrict__ pbf,
    unsigned short* __restrict__ nbf, float* __restrict__ stats)
{
    const int t    = threadIdx.x;
    const int wave = t >> 6, lane = t & 63;
    const int row  = blockIdx.x * 4 + wave;
    const size_t base = (size_t)row * DIM;

    const float4* a4 = (const float4*)(a + base);
    const float4* p4 = (const float4*)(p + base);
    const float4* n4 = (const float4*)(n + base);

    float v[8] = {0,0,0,0,0,0,0,0};   // sa qa sp qp sn qn dap2 dan2
#pragma unroll
    for (int c = 0; c < 4; c++) {
        const int idx = c * 64 + lane;
        const float4 va = a4[idx];
        const float4 vp = p4[idx];
        const float4 vn = n4[idx];
        const float fa[4] = {va.x, va.y, va.z, va.w};
        const float fp[4] = {vp.x, vp.y, vp.z, vp.w};
        const float fn[4] = {vn.x, vn.y, vn.z, vn.w};
#pragma unroll
        for (int e = 0; e < 4; e++) {
            v[0] += fa[e];           v[1] += fa[e] * fa[e];
            v[2] += fp[e];           v[3] += fp[e] * fp[e];
            v[4] += fn[e];           v[5] += fn[e] * fn[e];
            float dp = fa[e] - fp[e] + EPSF;  v[6] += dp * dp;
            float dn = fa[e] - fn[e] + EPSF;  v[7] += dn * dn;
        }
        ushort4 ba, bp, bn;
        ba.x = f2bf(fa[0]); ba.y = f2bf(fa[1]); ba.z = f2bf(fa[2]); ba.w = f2bf(fa[3]);
        bp.x = f2bf(fp[0]); bp.y = f2bf(fp[1]); bp.z = f2bf(fp[2]); bp.w = f2bf(fp[3]);
        bn.x = f2bf(fn[0]); bn.y = f2bf(fn[1]); bn.z = f2bf(fn[2]); bn.w = f2bf(fn[3]);
        ((ushort4*)(abf + base))[idx] = ba;
        ((ushort4*)(pbf + base))[idx] = bp;
        ((ushort4*)(nbf + base))[idx] = bn;
    }

#pragma unroll
    for (int m = 32; m >= 1; m >>= 1)
#pragma unroll
        for (int q = 0; q < 8; q++) v[q] += __shfl_xor(v[q], m);

    if (lane == 0) {
        stats[0 * NB + row] = v[1] + 2.0f * EPSF * v[0] + D_EPS2;  // base_a
        stats[1 * NB + row] = v[5] - 2.0f * EPSF * v[4];           // cn
        stats[2 * NB + row] = v[3] - 2.0f * EPSF * v[2];           // cp
        stats[3 * NB + row] = sqrtf(v[6]);                         // d_ap
        stats[4 * NB + row] = sqrtf(v[7]);                         // d_an_row
        ((unsigned*)stats)[5 * NB + row] = 0u;                     // hard_n
        ((unsigned*)stats)[6 * NB + row] = 0x7f800000u;            // hard_p
    }
}

// grid (2, 32, 32): x selects matrix (0=N masked-max, 1=P masked-min);
// y = j-tile (fast, clusters same-A-stripe blocks per XCD); z = i-tile.
__global__ __launch_bounds__(256, 3) void gemm_mask_kernel(
    const unsigned short* __restrict__ Abf,
    const unsigned short* __restrict__ Nbf,
    const unsigned short* __restrict__ Pbf,
    float* __restrict__ stats)
{
    const int  isP = blockIdx.x;
    const int  j0  = blockIdx.y * BM;
    const int  i0  = blockIdx.z * BM;
    const unsigned short* __restrict__ Bmat = isP ? Pbf : Nbf;

    __shared__ unsigned short sB[BM * BK];   // 16 KB only

    const int t    = threadIdx.x;
    const int wave = t >> 6, lane = t & 63;
    const int wm   = wave >> 1, wn = wave & 1;
    const int quad = lane >> 4, lrow = lane & 15;

    // ---- B staging: wave stages rows [wave*32, wave*32+32), 8 rows per g2l
    // (srow = lane>>3), 4 instrs per iter. slot s = lane&7 of row r holds
    // logical 16B chunk s ^ (r&7).
    const int srow = lane >> 3;
    const int kch  = ((lane & 7) ^ srow) * 8;
    const unsigned short* gB = Bmat + (size_t)(j0 + wave * 32 + srow) * DIM + kch;
    unsigned short* lB = sB + (wave * 32) * BK;

    // ---- A direct global->VGPR: frag row = lane&15, k-subchunk = quad*8
    const unsigned short* gA = Abf + (size_t)(i0 + wm * 64 + lrow) * DIM + (quad << 3);

    // ---- B fragment read: logical chunk c = half*4+quad, physical c^(lrow&7)
    const int rsw0 = ((0 + quad) ^ (lrow & 7)) * 8;
    const int rsw1 = ((4 + quad) ^ (lrow & 7)) * 8;
    const unsigned short* pb = sB + (wn * 64 + lrow) * BK;

    f32x4 acc[4][4];
#pragma unroll
    for (int im = 0; im < 4; im++)
#pragma unroll
        for (int jn = 0; jn < 4; jn++) acc[im][jn] = (f32x4)(0.0f);

    for (int kt = 0; kt < DIM; kt += BK) {
        __syncthreads();   // protect LDS from previous iteration's readers
#pragma unroll
        for (int g = 0; g < 4; g++)
            g2l16(gB + (size_t)kt + g * 8 * DIM, lB + g * 8 * BK);

        bf16x8 afr[2][4];
#pragma unroll
        for (int h = 0; h < 2; h++)
#pragma unroll
            for (int im = 0; im < 4; im++)
                afr[h][im] = *(const bf16x8*)(gA + kt + h * 32 + im * 16 * DIM);

        __syncthreads();   // drains vmcnt (g2l + A loads) before LDS reads

#pragma unroll
        for (int half = 0; half < 2; half++) {
            const int rsw = half ? rsw1 : rsw0;
            bf16x8 bfr[4];
#pragma unroll
            for (int jn = 0; jn < 4; jn++)
                bfr[jn] = *(const bf16x8*)(pb + jn * 16 * BK + rsw);
#pragma unroll
            for (int im = 0; im < 4; im++)
#pragma unroll
                for (int jn = 0; jn < 4; jn++)
                    acc[im][jn] = __builtin_amdgcn_mfma_f32_16x16x32_bf16(
                        afr[half][im], bfr[jn], acc[im][jn], 0, 0, 0);
        }
    }

    // epilogue (SQUARED domain): sq = base_a[i] + c[j] - 2*dot; monotone in
    // dist, so masks/extrema transfer; sqrt deferred to finalize.
    const float* __restrict__ base_a = stats + 0 * NB;
    const float* __restrict__ c_v    = isP ? (stats + 2 * NB) : (stats + 1 * NB);
    const float* __restrict__ cut_v  = isP ? (stats + 4 * NB) : (stats + 3 * NB);
    unsigned* __restrict__ hard = ((unsigned*)stats) + (isP ? 6 : 5) * NB;

#pragma unroll
    for (int im = 0; im < 4; im++) {
#pragma unroll
        for (int r = 0; r < 4; r++) {
            const int gi = i0 + wm * 64 + im * 16 + quad * 4 + r;
            const float cut  = cut_v[gi];
            const float cut2 = cut * cut;
            const float bi   = base_a[gi];
            float best = isP ? __uint_as_float(0x7f800000u) : 0.0f;
#pragma unroll
            for (int jn = 0; jn < 4; jn++) {
                const int gj = j0 + wn * 64 + jn * 16 + lrow;
                const float sq = fmaxf(bi + c_v[gj] - 2.0f * acc[im][jn][r], 0.0f);
                if (isP) { if (sq > cut2 && sq < best) best = sq; }
                else     { if (sq < cut2 && sq > best) best = sq; }
            }
#pragma unroll
            for (int m = 1; m < 16; m <<= 1) {
                float o = __shfl_xor(best, m);
                best = isP ? fminf(best, o) : fmaxf(best, o);
            }
            if (lrow == 0) {
                const unsigned bits = __float_as_uint(best);
                if (isP) { if (bits != 0x7f800000u) atomicMin(hard + gi, bits); }
                else     { if (bits != 0u)          atomicMax(hard + gi, bits); }
            }
        }
    }
}

__global__ __launch_bounds__(1024) void finalize_kernel(
    const float* __restrict__ stats, float* __restrict__ out)
{
    const unsigned* hard_n = ((const unsigned*)stats) + 5 * NB;
    const unsigned* hard_p = ((const unsigned*)stats) + 6 * NB;
    const float*    d_ap   = stats + 3 * NB;
    const int t = threadIdx.x;
    const int wave = t >> 6, lane = t & 63;
    __shared__ float pn[16], pp[16];
    __shared__ float s_dan, s_dpp;

    float sn = 0.0f, sp = 0.0f;
    for (int i = t; i < NB; i += 1024) {
        sn += sqrtf(__uint_as_float(hard_n[i]));          // sq -> dist (0 -> 0)
        const unsigned hp = hard_p[i];
        if (hp != 0x7f800000u) sp += sqrtf(__uint_as_float(hp));
    }
#pragma unroll
    for (int m = 32; m >= 1; m >>= 1) {
        sn += __shfl_xor(sn, m);
        sp += __shfl_xor(sp, m);
    }
    if (lane == 0) { pn[wave] = sn; pp[wave] = sp; }
    __syncthreads();
    if (t == 0) {
        float an = 0.0f, ap = 0.0f;
#pragma unroll
        for (int w = 0; w < 16; w++) { an += pn[w]; ap += pp[w]; }
        s_dan = an / (float)NB;
        s_dpp = ap / (float)NB;
    }
    __syncthreads();
    const float dan = s_dan, dpp = s_dpp;

    float accv = 0.0f;
    for (int i = t; i < NB; i += 1024)
        accv += fmaxf(d_ap[i] - 0.5f * dpp - 0.5f * dan + 1.0f, 0.0f);
#pragma unroll
    for (int m = 32; m >= 1; m >>= 1) accv += __shfl_xor(accv, m);
    if (lane == 0) pn[wave] = accv;
    __syncthreads();
    if (t == 0) {
        float s = 0.0f;
#pragma unroll
        for (int w = 0; w < 16; w++) s += pn[w];
        out[0] = s / (float)NB;
    }
}

extern "C" void kernel_launch(void* const* d_in, const int* in_sizes, int n_in,
                              void* d_out, int out_size, void* d_ws, size_t ws_size,
                              hipStream_t stream) {
    const float* a = (const float*)d_in[0];
    const float* p = (const float*)d_in[1];
    const float* n = (const float*)d_in[2];
    float* out = (float*)d_out;

    // ws layout: abf | pbf | nbf | stats(7*NB floats)  => ~25.3 MB
    unsigned short* abf = (unsigned short*)d_ws;
    unsigned short* pbf = abf + (size_t)NB * DIM;
    unsigned short* nbf = pbf + (size_t)NB * DIM;
    float* stats = (float*)(nbf + (size_t)NB * DIM);

    row_stats_kernel<<<NB / 4, 256, 0, stream>>>(a, p, n, abf, pbf, nbf, stats);

    dim3 grid(2, NB / BM, NB / BM);
    gemm_mask_kernel<<<grid, 256, 0, stream>>>(abf, nbf, pbf, stats);

    finalize_kernel<<<1, 1024, 0, stream>>>(stats, out);
}

// Round 7
// 250.816 us; speedup vs baseline: 1.0350x; 1.0350x over previous
//
#include <hip/hip_runtime.h>

// ---------------------------------------------------------------------------
// TripletLossWithHardMining  (B=4096, D=1024, fp32 in, fp32 scalar out)
//
//  K2 gemm_mask (R7): software-pipelined fused GEMM, NO __syncthreads in the
//  K-loop. Window k (BK=64): compute buf[k&1] while window k+1 is in flight
//  and window k+2 is being issued. Ordering via raw s_barrier + manual
//  s_waitcnt vmcnt(16) (never 0 until the final peel).
//   - N/P tiles: 2-deep LDS buffers (2 x 16 KB x 2 mats = 64 KB total),
//     global_load_lds(16B) + XOR chunk swizzle (slot = chunk ^ (row&7)).
//   - A fragments: direct global->VGPR (R6-verified MFMA A-layout), 2-deep
//     register pipeline afr[2][2][4].
//   - Per wave per window: 8 g2l + 8 A-loads = 16 VMEM; vmcnt(16) after
//     issuing k+2 guarantees k+1 retired (FIFO).
//  Epilogue in squared-distance domain; atomicMax/Min on uint bits.
//
//  Dead-ends: R4 barrier-free 1-iter-prefetch (184us); R6 unfused (182us,
//  halved MFMA/window). R5 fused single-buffer = 96.5us baseline.
// ---------------------------------------------------------------------------

#define NB 4096
#define DIM 1024
#define EPSF 1e-6f
#define D_EPS2 (1024.0f * 1e-6f * 1e-6f)

#define BM 128           // block tile (rows and cols)
#define BK 64            // k-tile (bf16 elems) -> 128 B rows, unpadded

typedef __bf16  bf16x8 __attribute__((ext_vector_type(8)));
typedef float   f32x4  __attribute__((ext_vector_type(4)));

__device__ __forceinline__ unsigned short f2bf(float x) {
    unsigned u = __float_as_uint(x);
    u += 0x7FFFu + ((u >> 16) & 1u);   // round-to-nearest-even
    return (unsigned short)(u >> 16);
}

// async 16B/lane global->LDS; lds base wave-uniform, data lands at base+lane*16
__device__ __forceinline__ void g2l16(const unsigned short* g, unsigned short* l) {
    __builtin_amdgcn_global_load_lds(
        (const __attribute__((address_space(1))) unsigned int*)g,
        (__attribute__((address_space(3))) unsigned int*)l, 16, 0, 0);
}

#define FENCE      asm volatile("" ::: "memory")
#define WAITVM16   asm volatile("s_waitcnt vmcnt(16)" ::: "memory")
#define WAITVM0    asm volatile("s_waitcnt vmcnt(0)" ::: "memory")
#define BARRIER    asm volatile("s_barrier" ::: "memory")
#define BARRIER_LG asm volatile("s_waitcnt lgkmcnt(0)\n\ts_barrier" ::: "memory")

// stats layout (NB-float slots):
// 0: base_a[i] = |a_i|^2 + 2e*sum_a + D*e^2
// 1: cn[j]     = |n_j|^2 - 2e*sum_n
// 2: cp[j]     = |p_j|^2 - 2e*sum_p
// 3: d_ap   4: d_an_row   5: hard_n bits (sq)   6: hard_p bits (sq)

// wave-per-row: 1024 blocks x 4 waves
__global__ __launch_bounds__(256) void row_stats_kernel(
    const float* __restrict__ a, const float* __restrict__ p,
    const float* __restrict__ n,
    unsigned short* __restrict__ abf, unsigned short* __restrict__ pbf,
    unsigned short* __restrict__ nbf, float* __restrict__ stats)
{
    const int t    = threadIdx.x;
    const int wave = t >> 6, lane = t & 63;
    const int row  = blockIdx.x * 4 + wave;
    const size_t base = (size_t)row * DIM;

    const float4* a4 = (const float4*)(a + base);
    const float4* p4 = (const float4*)(p + base);
    const float4* n4 = (const float4*)(n + base);

    float v[8] = {0,0,0,0,0,0,0,0};   // sa qa sp qp sn qn dap2 dan2
#pragma unroll
    for (int c = 0; c < 4; c++) {
        const int idx = c * 64 + lane;
        const float4 va = a4[idx];
        const float4 vp = p4[idx];
        const float4 vn = n4[idx];
        const float fa[4] = {va.x, va.y, va.z, va.w};
        const float fp[4] = {vp.x, vp.y, vp.z, vp.w};
        const float fn[4] = {vn.x, vn.y, vn.z, vn.w};
#pragma unroll
        for (int e = 0; e < 4; e++) {
            v[0] += fa[e];           v[1] += fa[e] * fa[e];
            v[2] += fp[e];           v[3] += fp[e] * fp[e];
            v[4] += fn[e];           v[5] += fn[e] * fn[e];
            float dp = fa[e] - fp[e] + EPSF;  v[6] += dp * dp;
            float dn = fa[e] - fn[e] + EPSF;  v[7] += dn * dn;
        }
        ushort4 ba, bp, bn;
        ba.x = f2bf(fa[0]); ba.y = f2bf(fa[1]); ba.z = f2bf(fa[2]); ba.w = f2bf(fa[3]);
        bp.x = f2bf(fp[0]); bp.y = f2bf(fp[1]); bp.z = f2bf(fp[2]); bp.w = f2bf(fp[3]);
        bn.x = f2bf(fn[0]); bn.y = f2bf(fn[1]); bn.z = f2bf(fn[2]); bn.w = f2bf(fn[3]);
        ((ushort4*)(abf + base))[idx] = ba;
        ((ushort4*)(pbf + base))[idx] = bp;
        ((ushort4*)(nbf + base))[idx] = bn;
    }

#pragma unroll
    for (int m = 32; m >= 1; m >>= 1)
#pragma unroll
        for (int q = 0; q < 8; q++) v[q] += __shfl_xor(v[q], m);

    if (lane == 0) {
        stats[0 * NB + row] = v[1] + 2.0f * EPSF * v[0] + D_EPS2;  // base_a
        stats[1 * NB + row] = v[5] - 2.0f * EPSF * v[4];           // cn
        stats[2 * NB + row] = v[3] - 2.0f * EPSF * v[2];           // cp
        stats[3 * NB + row] = sqrtf(v[6]);                         // d_ap
        stats[4 * NB + row] = sqrtf(v[7]);                         // d_an_row
        ((unsigned*)stats)[5 * NB + row] = 0u;                     // hard_n
        ((unsigned*)stats)[6 * NB + row] = 0x7f800000u;            // hard_p
    }
}

// grid (32, 32): x = j-tile (fast -> same-i stripes cluster), y = i-tile.
// Fused: block computes both A.N^T and A.P^T for its 128x128 tile.
__global__ __launch_bounds__(256) void gemm_mask_kernel(
    const unsigned short* __restrict__ Abf,
    const unsigned short* __restrict__ Nbf,
    const unsigned short* __restrict__ Pbf,
    float* __restrict__ stats)
{
    const int j0 = blockIdx.x * BM;
    const int i0 = blockIdx.y * BM;

    __shared__ unsigned short sN[2][BM * BK];   // 2 x 16 KB
    __shared__ unsigned short sP[2][BM * BK];   // 2 x 16 KB  -> 64 KB total

    const int t    = threadIdx.x;
    const int wave = t >> 6, lane = t & 63;
    const int wm   = wave >> 1, wn = wave & 1;
    const int quad = lane >> 4, lrow = lane & 15;

    // ---- B staging (per wave: rows [wave*32, wave*32+32), 4 g2l per mat).
    // slot s = lane&7 of row r holds logical 16B chunk s ^ (r&7).
    const int srow = lane >> 3;
    const int kch  = ((lane & 7) ^ srow) * 8;
    const unsigned short* gN = Nbf + (size_t)(j0 + wave * 32 + srow) * DIM + kch;
    const unsigned short* gP = Pbf + (size_t)(j0 + wave * 32 + srow) * DIM + kch;
    const int lbase = (wave * 32) * BK;

    // ---- A direct global->VGPR: frag row = lane&15, k-subchunk = quad*8
    const unsigned short* gA = Abf + (size_t)(i0 + wm * 64 + lrow) * DIM + (quad << 3);

    // ---- B fragment read: logical chunk c = half*4+quad, physical c^(lrow&7)
    const int rsw0 = ((0 + quad) ^ (lrow & 7)) * 8;
    const int rsw1 = ((4 + quad) ^ (lrow & 7)) * 8;
    const int pboff = (wn * 64 + lrow) * BK;

    bf16x8 afr[2][2][4];      // [buf][half][im]
    f32x4 accN[4][4], accP[4][4];
#pragma unroll
    for (int im = 0; im < 4; im++)
#pragma unroll
        for (int jn = 0; jn < 4; jn++) {
            accN[im][jn] = (f32x4)(0.0f);
            accP[im][jn] = (f32x4)(0.0f);
        }

    // issue window kw_ into buffer b_: 8 g2l (N,P) + 8 A-loads = 16 VMEM
#define ISSUE(kw_, b_) do {                                                   \
    const unsigned short* _gn = gN + (size_t)(kw_) * BK;                      \
    const unsigned short* _gp = gP + (size_t)(kw_) * BK;                      \
    unsigned short* _ln = &sN[(b_)][lbase];                                   \
    unsigned short* _lp = &sP[(b_)][lbase];                                   \
    _Pragma("unroll")                                                         \
    for (int g = 0; g < 4; g++) {                                             \
        g2l16(_gn + (size_t)g * 8 * DIM, _ln + g * 8 * BK);                   \
        g2l16(_gp + (size_t)g * 8 * DIM, _lp + g * 8 * BK);                   \
    }                                                                         \
    const unsigned short* _ga = gA + (size_t)(kw_) * BK;                      \
    _Pragma("unroll")                                                         \
    for (int h = 0; h < 2; h++)                                               \
        _Pragma("unroll")                                                     \
        for (int im = 0; im < 4; im++)                                        \
            afr[(b_)][h][im] = *(const bf16x8*)(_ga + h * 32 + im * 16 * DIM);\
} while (0)

#define COMPUTE(b_) do {                                                      \
    _Pragma("unroll")                                                         \
    for (int half = 0; half < 2; half++) {                                    \
        const int rsw = half ? rsw1 : rsw0;                                   \
        bf16x8 bnfr[4], bpfr[4];                                              \
        _Pragma("unroll")                                                     \
        for (int jn = 0; jn < 4; jn++) {                                      \
            bnfr[jn] = *(const bf16x8*)(&sN[(b_)][pboff + jn * 16 * BK + rsw]);\
            bpfr[jn] = *(const bf16x8*)(&sP[(b_)][pboff + jn * 16 * BK + rsw]);\
        }                                                                     \
        _Pragma("unroll")                                                     \
        for (int im = 0; im < 4; im++)                                        \
            _Pragma("unroll")                                                 \
            for (int jn = 0; jn < 4; jn++) {                                  \
                accN[im][jn] = __builtin_amdgcn_mfma_f32_16x16x32_bf16(       \
                    afr[(b_)][half][im], bnfr[jn], accN[im][jn], 0, 0, 0);    \
                accP[im][jn] = __builtin_amdgcn_mfma_f32_16x16x32_bf16(       \
                    afr[(b_)][half][im], bpfr[jn], accP[im][jn], 0, 0, 0);    \
            }                                                                 \
    }                                                                         \
} while (0)

    // ---- prologue: windows 0 and 1 in flight; wait for 0 ----
    ISSUE(0, 0);
    FENCE;
    ISSUE(1, 1);
    WAITVM16;     // window 0 retired (16 newest = window 1 still allowed)
    BARRIER;      // all waves' window 0 landed

    // ---- steady loop: windows 0..13 (7 pairs) ----
    for (int kp = 0; kp < 7; kp++) {
        COMPUTE(0);
        BARRIER_LG;                 // all readers done with buf0
        ISSUE(2 * kp + 2, 0);
        WAITVM16;                   // window 2kp+1 retired
        BARRIER;

        COMPUTE(1);
        BARRIER_LG;                 // all readers done with buf1
        ISSUE(2 * kp + 3, 1);
        WAITVM16;                   // window 2kp+2 retired
        BARRIER;
    }
    // ---- peel: windows 14, 15 ----
    COMPUTE(0);
    BARRIER_LG;
    WAITVM0;                        // drain window 15
    BARRIER;
    COMPUTE(1);

#undef COMPUTE
#undef ISSUE

    // epilogue (SQUARED domain): sq = base_a[i] + c[j] - 2*dot
    const float* __restrict__ base_a = stats + 0 * NB;
    const float* __restrict__ cn_v   = stats + 1 * NB;
    const float* __restrict__ cp_v   = stats + 2 * NB;
    const float* __restrict__ d_ap   = stats + 3 * NB;
    const float* __restrict__ d_an   = stats + 4 * NB;
    unsigned* __restrict__ hard_n = ((unsigned*)stats) + 5 * NB;
    unsigned* __restrict__ hard_p = ((unsigned*)stats) + 6 * NB;

#pragma unroll
    for (int im = 0; im < 4; im++) {
#pragma unroll
        for (int r = 0; r < 4; r++) {
            const int gi = i0 + wm * 64 + im * 16 + quad * 4 + r;
            const float cutN = d_ap[gi];
            const float cutP = d_an[gi];
            const float cutN2 = cutN * cutN;
            const float cutP2 = cutP * cutP;
            const float bi    = base_a[gi];
            float bestN = 0.0f;
            float bestP = __uint_as_float(0x7f800000u);
#pragma unroll
            for (int jn = 0; jn < 4; jn++) {
                const int gj = j0 + wn * 64 + jn * 16 + lrow;
                const float sqN = fmaxf(bi + cn_v[gj] - 2.0f * accN[im][jn][r], 0.0f);
                const float sqP = fmaxf(bi + cp_v[gj] - 2.0f * accP[im][jn][r], 0.0f);
                if (sqN < cutN2 && sqN > bestN) bestN = sqN;
                if (sqP > cutP2 && sqP < bestP) bestP = sqP;
            }
#pragma unroll
            for (int m = 1; m < 16; m <<= 1) {
                bestN = fmaxf(bestN, __shfl_xor(bestN, m));
                bestP = fminf(bestP, __shfl_xor(bestP, m));
            }
            if (lrow == 0) {
                const unsigned bn_ = __float_as_uint(bestN);
                const unsigned bp_ = __float_as_uint(bestP);
                if (bn_ != 0u)          atomicMax(hard_n + gi, bn_);
                if (bp_ != 0x7f800000u) atomicMin(hard_p + gi, bp_);
            }
        }
    }
}

__global__ __launch_bounds__(1024) void finalize_kernel(
    const float* __restrict__ stats, float* __restrict__ out)
{
    const unsigned* hard_n = ((const unsigned*)stats) + 5 * NB;
    const unsigned* hard_p = ((const unsigned*)stats) + 6 * NB;
    const float*    d_ap   = stats + 3 * NB;
    const int t = threadIdx.x;
    const int wave = t >> 6, lane = t & 63;
    __shared__ float pn[16], pp[16];
    __shared__ float s_dan, s_dpp;

    float sn = 0.0f, sp = 0.0f;
    for (int i = t; i < NB; i += 1024) {
        sn += sqrtf(__uint_as_float(hard_n[i]));          // sq -> dist (0 -> 0)
        const unsigned hp = hard_p[i];
        if (hp != 0x7f800000u) sp += sqrtf(__uint_as_float(hp));
    }
#pragma unroll
    for (int m = 32; m >= 1; m >>= 1) {
        sn += __shfl_xor(sn, m);
        sp += __shfl_xor(sp, m);
    }
    if (lane == 0) { pn[wave] = sn; pp[wave] = sp; }
    __syncthreads();
    if (t == 0) {
        float an = 0.0f, ap = 0.0f;
#pragma unroll
        for (int w = 0; w < 16; w++) { an += pn[w]; ap += pp[w]; }
        s_dan = an / (float)NB;
        s_dpp = ap / (float)NB;
    }
    __syncthreads();
    const float dan = s_dan, dpp = s_dpp;

    float accv = 0.0f;
    for (int i = t; i < NB; i += 1024)
        accv += fmaxf(d_ap[i] - 0.5f * dpp - 0.5f * dan + 1.0f, 0.0f);
#pragma unroll
    for (int m = 32; m >= 1; m >>= 1) accv += __shfl_xor(accv, m);
    if (lane == 0) pn[wave] = accv;
    __syncthreads();
    if (t == 0) {
        float s = 0.0f;
#pragma unroll
        for (int w = 0; w < 16; w++) s += pn[w];
        out[0] = s / (float)NB;
    }
}

extern "C" void kernel_launch(void* const* d_in, const int* in_sizes, int n_in,
                              void* d_out, int out_size, void* d_ws, size_t ws_size,
                              hipStream_t stream) {
    const float* a = (const float*)d_in[0];
    const float* p = (const float*)d_in[1];
    const float* n = (const float*)d_in[2];
    float* out = (float*)d_out;

    // ws layout: abf | pbf | nbf | stats(7*NB floats)  => ~25.3 MB
    unsigned short* abf = (unsigned short*)d_ws;
    unsigned short* pbf = abf + (size_t)NB * DIM;
    unsigned short* nbf = pbf + (size_t)NB * DIM;
    float* stats = (float*)(nbf + (size_t)NB * DIM);

    row_stats_kernel<<<NB / 4, 256, 0, stream>>>(a, p, n, abf, pbf, nbf, stats);

    dim3 grid(NB / BM, NB / BM);
    gemm_mask_kernel<<<grid, 256, 0, stream>>>(abf, nbf, pbf, stats);

    finalize_kernel<<<1, 1024, 0, stream>>>(stats, out);
}

// Round 8
// 197.145 us; speedup vs baseline: 1.3167x; 1.2722x over previous
//
#include <hip/hip_runtime.h>

// ---------------------------------------------------------------------------
// TripletLossWithHardMining  (B=4096, D=1024, fp32 in, fp32 scalar out)
//
//  K2 gemm_mask (R8): R5's fused single-buffer BK=64 structure (best: 96.5us)
//  with LDS traffic cut ~3x:
//   - A fragments DIRECT global->VGPR (R6-verified: MFMA A-layout is
//     row-major 16B chunks) -> no A LDS write, no 2x A LDS read.
//   - N/P staged via global_load_lds(16B) + XOR chunk swizzle (R5-verified,
//     0 bank conflicts).
//   - JIT B-fragment loads (8 live B regs, not 32) to stay under the
//     256-reg/wave cliff (R7 lesson: 168 VGPR + 128 AGPR -> 1 wave/SIMD).
//  Epilogue in squared-distance domain; atomicMax/Min on uint bits.
//
//  Dead-ends: R4 barrier-free per-wave pipeline (184us); R6 unfused (182us,
//  halved MFMA/window); R7 dbuf+vmcnt pipeline (169us, reg cliff).
// ---------------------------------------------------------------------------

#define NB 4096
#define DIM 1024
#define EPSF 1e-6f
#define D_EPS2 (1024.0f * 1e-6f * 1e-6f)

#define BM 128           // block tile (rows and cols)
#define BK 64            // k-tile (bf16 elems) -> 128 B rows, unpadded

typedef __bf16  bf16x8 __attribute__((ext_vector_type(8)));
typedef float   f32x4  __attribute__((ext_vector_type(4)));

__device__ __forceinline__ unsigned short f2bf(float x) {
    unsigned u = __float_as_uint(x);
    u += 0x7FFFu + ((u >> 16) & 1u);   // round-to-nearest-even
    return (unsigned short)(u >> 16);
}

// async 16B/lane global->LDS; lds base wave-uniform, data lands at base+lane*16
__device__ __forceinline__ void g2l16(const unsigned short* g, unsigned short* l) {
    __builtin_amdgcn_global_load_lds(
        (const __attribute__((address_space(1))) unsigned int*)g,
        (__attribute__((address_space(3))) unsigned int*)l, 16, 0, 0);
}

// stats layout (NB-float slots):
// 0: base_a[i] = |a_i|^2 + 2e*sum_a + D*e^2
// 1: cn[j]     = |n_j|^2 - 2e*sum_n
// 2: cp[j]     = |p_j|^2 - 2e*sum_p
// 3: d_ap   4: d_an_row   5: hard_n bits (sq)   6: hard_p bits (sq)

// wave-per-row: 1024 blocks x 4 waves
__global__ __launch_bounds__(256) void row_stats_kernel(
    const float* __restrict__ a, const float* __restrict__ p,
    const float* __restrict__ n,
    unsigned short* __restrict__ abf, unsigned short* __restrict__ pbf,
    unsigned short* __restrict__ nbf, float* __restrict__ stats)
{
    const int t    = threadIdx.x;
    const int wave = t >> 6, lane = t & 63;
    const int row  = blockIdx.x * 4 + wave;
    const size_t base = (size_t)row * DIM;

    const float4* a4 = (const float4*)(a + base);
    const float4* p4 = (const float4*)(p + base);
    const float4* n4 = (const float4*)(n + base);

    float v[8] = {0,0,0,0,0,0,0,0};   // sa qa sp qp sn qn dap2 dan2
#pragma unroll
    for (int c = 0; c < 4; c++) {
        const int idx = c * 64 + lane;
        const float4 va = a4[idx];
        const float4 vp = p4[idx];
        const float4 vn = n4[idx];
        const float fa[4] = {va.x, va.y, va.z, va.w};
        const float fp[4] = {vp.x, vp.y, vp.z, vp.w};
        const float fn[4] = {vn.x, vn.y, vn.z, vn.w};
#pragma unroll
        for (int e = 0; e < 4; e++) {
            v[0] += fa[e];           v[1] += fa[e] * fa[e];
            v[2] += fp[e];           v[3] += fp[e] * fp[e];
            v[4] += fn[e];           v[5] += fn[e] * fn[e];
            float dp = fa[e] - fp[e] + EPSF;  v[6] += dp * dp;
            float dn = fa[e] - fn[e] + EPSF;  v[7] += dn * dn;
        }
        ushort4 ba, bp, bn;
        ba.x = f2bf(fa[0]); ba.y = f2bf(fa[1]); ba.z = f2bf(fa[2]); ba.w = f2bf(fa[3]);
        bp.x = f2bf(fp[0]); bp.y = f2bf(fp[1]); bp.z = f2bf(fp[2]); bp.w = f2bf(fp[3]);
        bn.x = f2bf(fn[0]); bn.y = f2bf(fn[1]); bn.z = f2bf(fn[2]); bn.w = f2bf(fn[3]);
        ((ushort4*)(abf + base))[idx] = ba;
        ((ushort4*)(pbf + base))[idx] = bp;
        ((ushort4*)(nbf + base))[idx] = bn;
    }

#pragma unroll
    for (int m = 32; m >= 1; m >>= 1)
#pragma unroll
        for (int q = 0; q < 8; q++) v[q] += __shfl_xor(v[q], m);

    if (lane == 0) {
        stats[0 * NB + row] = v[1] + 2.0f * EPSF * v[0] + D_EPS2;  // base_a
        stats[1 * NB + row] = v[5] - 2.0f * EPSF * v[4];           // cn
        stats[2 * NB + row] = v[3] - 2.0f * EPSF * v[2];           // cp
        stats[3 * NB + row] = sqrtf(v[6]);                         // d_ap
        stats[4 * NB + row] = sqrtf(v[7]);                         // d_an_row
        ((unsigned*)stats)[5 * NB + row] = 0u;                     // hard_n
        ((unsigned*)stats)[6 * NB + row] = 0x7f800000u;            // hard_p
    }
}

// grid (32, 32): x = j-tile (fast), y = i-tile. Fused N+P per block.
__global__ __launch_bounds__(256, 2) void gemm_mask_kernel(
    const unsigned short* __restrict__ Abf,
    const unsigned short* __restrict__ Nbf,
    const unsigned short* __restrict__ Pbf,
    float* __restrict__ stats)
{
    const int j0 = blockIdx.x * BM;
    const int i0 = blockIdx.y * BM;

    __shared__ unsigned short sN[BM * BK];   // 16 KB each -> 32 KB total
    __shared__ unsigned short sP[BM * BK];

    const int t    = threadIdx.x;
    const int wave = t >> 6, lane = t & 63;
    const int wm   = wave >> 1, wn = wave & 1;
    const int quad = lane >> 4, lrow = lane & 15;

    // ---- N/P staging: wave stages rows [wave*32, wave*32+32), 8 rows per
    // g2l (srow = lane>>3), 4 instrs per mat per iter. slot s = lane&7 of
    // row r holds logical 16B chunk s ^ (r&7).
    const int srow = lane >> 3;
    const int kch  = ((lane & 7) ^ srow) * 8;
    const unsigned short* gN = Nbf + (size_t)(j0 + wave * 32 + srow) * DIM + kch;
    const unsigned short* gP = Pbf + (size_t)(j0 + wave * 32 + srow) * DIM + kch;
    unsigned short* lN = sN + (wave * 32) * BK;
    unsigned short* lP = sP + (wave * 32) * BK;

    // ---- A direct global->VGPR: frag row = lane&15, k-subchunk = quad*8
    const unsigned short* gA = Abf + (size_t)(i0 + wm * 64 + lrow) * DIM + (quad << 3);

    // ---- B fragment read: logical chunk c = half*4+quad, physical c^(lrow&7)
    const int rsw0 = ((0 + quad) ^ (lrow & 7)) * 8;
    const int rsw1 = ((4 + quad) ^ (lrow & 7)) * 8;
    const unsigned short* pbn = sN + (wn * 64 + lrow) * BK;
    const unsigned short* pbp = sP + (wn * 64 + lrow) * BK;

    f32x4 accN[4][4], accP[4][4];
#pragma unroll
    for (int im = 0; im < 4; im++)
#pragma unroll
        for (int jn = 0; jn < 4; jn++) {
            accN[im][jn] = (f32x4)(0.0f);
            accP[im][jn] = (f32x4)(0.0f);
        }

    for (int kt = 0; kt < DIM; kt += BK) {
        __syncthreads();   // protect LDS from previous iteration's readers
#pragma unroll
        for (int g = 0; g < 4; g++) {
            g2l16(gN + (size_t)kt + g * 8 * DIM, lN + g * 8 * BK);
            g2l16(gP + (size_t)kt + g * 8 * DIM, lP + g * 8 * BK);
        }
        // A fragments for both halves, direct to VGPR (8 x dwordx4)
        bf16x8 afr[2][4];
#pragma unroll
        for (int h = 0; h < 2; h++)
#pragma unroll
            for (int im = 0; im < 4; im++)
                afr[h][im] = *(const bf16x8*)(gA + kt + h * 32 + im * 16 * DIM);

        __syncthreads();   // drains vmcnt (g2l + A loads) before LDS reads

#pragma unroll
        for (int half = 0; half < 2; half++) {
            const int rsw = half ? rsw1 : rsw0;
#pragma unroll
            for (int jn = 0; jn < 4; jn++) {      // JIT B: 8 live B regs
                const bf16x8 bnfr = *(const bf16x8*)(pbn + jn * 16 * BK + rsw);
                const bf16x8 bpfr = *(const bf16x8*)(pbp + jn * 16 * BK + rsw);
#pragma unroll
                for (int im = 0; im < 4; im++) {
                    accN[im][jn] = __builtin_amdgcn_mfma_f32_16x16x32_bf16(
                        afr[half][im], bnfr, accN[im][jn], 0, 0, 0);
                    accP[im][jn] = __builtin_amdgcn_mfma_f32_16x16x32_bf16(
                        afr[half][im], bpfr, accP[im][jn], 0, 0, 0);
                }
            }
        }
    }

    // epilogue (SQUARED domain): sq = base_a[i] + c[j] - 2*dot
    const float* __restrict__ base_a = stats + 0 * NB;
    const float* __restrict__ cn_v   = stats + 1 * NB;
    const float* __restrict__ cp_v   = stats + 2 * NB;
    const float* __restrict__ d_ap   = stats + 3 * NB;
    const float* __restrict__ d_an   = stats + 4 * NB;
    unsigned* __restrict__ hard_n = ((unsigned*)stats) + 5 * NB;
    unsigned* __restrict__ hard_p = ((unsigned*)stats) + 6 * NB;

#pragma unroll
    for (int im = 0; im < 4; im++) {
#pragma unroll
        for (int r = 0; r < 4; r++) {
            const int gi = i0 + wm * 64 + im * 16 + quad * 4 + r;
            const float cutN = d_ap[gi];
            const float cutP = d_an[gi];
            const float cutN2 = cutN * cutN;
            const float cutP2 = cutP * cutP;
            const float bi    = base_a[gi];
            float bestN = 0.0f;
            float bestP = __uint_as_float(0x7f800000u);
#pragma unroll
            for (int jn = 0; jn < 4; jn++) {
                const int gj = j0 + wn * 64 + jn * 16 + lrow;
                const float sqN = fmaxf(bi + cn_v[gj] - 2.0f * accN[im][jn][r], 0.0f);
                const float sqP = fmaxf(bi + cp_v[gj] - 2.0f * accP[im][jn][r], 0.0f);
                if (sqN < cutN2 && sqN > bestN) bestN = sqN;
                if (sqP > cutP2 && sqP < bestP) bestP = sqP;
            }
#pragma unroll
            for (int m = 1; m < 16; m <<= 1) {
                bestN = fmaxf(bestN, __shfl_xor(bestN, m));
                bestP = fminf(bestP, __shfl_xor(bestP, m));
            }
            if (lrow == 0) {
                const unsigned bn_ = __float_as_uint(bestN);
                const unsigned bp_ = __float_as_uint(bestP);
                if (bn_ != 0u)          atomicMax(hard_n + gi, bn_);
                if (bp_ != 0x7f800000u) atomicMin(hard_p + gi, bp_);
            }
        }
    }
}

__global__ __launch_bounds__(1024) void finalize_kernel(
    const float* __restrict__ stats, float* __restrict__ out)
{
    const unsigned* hard_n = ((const unsigned*)stats) + 5 * NB;
    const unsigned* hard_p = ((const unsigned*)stats) + 6 * NB;
    const float*    d_ap   = stats + 3 * NB;
    const int t = threadIdx.x;
    const int wave = t >> 6, lane = t & 63;
    __shared__ float pn[16], pp[16];
    __shared__ float s_dan, s_dpp;

    float sn = 0.0f, sp = 0.0f;
    for (int i = t; i < NB; i += 1024) {
        sn += sqrtf(__uint_as_float(hard_n[i]));          // sq -> dist (0 -> 0)
        const unsigned hp = hard_p[i];
        if (hp != 0x7f800000u) sp += sqrtf(__uint_as_float(hp));
    }
#pragma unroll
    for (int m = 32; m >= 1; m >>= 1) {
        sn += __shfl_xor(sn, m);
        sp += __shfl_xor(sp, m);
    }
    if (lane == 0) { pn[wave] = sn; pp[wave] = sp; }
    __syncthreads();
    if (t == 0) {
        float an = 0.0f, ap = 0.0f;
#pragma unroll
        for (int w = 0; w < 16; w++) { an += pn[w]; ap += pp[w]; }
        s_dan = an / (float)NB;
        s_dpp = ap / (float)NB;
    }
    __syncthreads();
    const float dan = s_dan, dpp = s_dpp;

    float accv = 0.0f;
    for (int i = t; i < NB; i += 1024)
        accv += fmaxf(d_ap[i] - 0.5f * dpp - 0.5f * dan + 1.0f, 0.0f);
#pragma unroll
    for (int m = 32; m >= 1; m >>= 1) accv += __shfl_xor(accv, m);
    if (lane == 0) pn[wave] = accv;
    __syncthreads();
    if (t == 0) {
        float s = 0.0f;
#pragma unroll
        for (int w = 0; w < 16; w++) s += pn[w];
        out[0] = s / (float)NB;
    }
}

extern "C" void kernel_launch(void* const* d_in, const int* in_sizes, int n_in,
                              void* d_out, int out_size, void* d_ws, size_t ws_size,
                              hipStream_t stream) {
    const float* a = (const float*)d_in[0];
    const float* p = (const float*)d_in[1];
    const float* n = (const float*)d_in[2];
    float* out = (float*)d_out;

    // ws layout: abf | pbf | nbf | stats(7*NB floats)  => ~25.3 MB
    unsigned short* abf = (unsigned short*)d_ws;
    unsigned short* pbf = abf + (size_t)NB * DIM;
    unsigned short* nbf = pbf + (size_t)NB * DIM;
    float* stats = (float*)(nbf + (size_t)NB * DIM);

    row_stats_kernel<<<NB / 4, 256, 0, stream>>>(a, p, n, abf, pbf, nbf, stats);

    dim3 grid(NB / BM, NB / BM);
    gemm_mask_kernel<<<grid, 256, 0, stream>>>(abf, nbf, pbf, stats);

    finalize_kernel<<<1, 1024, 0, stream>>>(stats, out);
}

// Round 9
// 196.210 us; speedup vs baseline: 1.3230x; 1.0048x over previous
//
#include <hip/hip_runtime.h>

// ---------------------------------------------------------------------------
// TripletLossWithHardMining  (B=4096, D=1024, fp32 in, fp32 scalar out)
//
//  K2 gemm_mask (R9): fused 128x128 tile, BK=64, TRUE software pipeline:
//   - N/P double-buffered in LDS: 2 bufs x (16+16) KB = 64 KB (A not in LDS
//     -> dbuf fits; 2 blocks/CU preserved).
//   - A fragments direct global->VGPR (R6/R8-verified layout), reloaded
//     per-half right after last use (peak 8 b128 = 32 VGPR).
//   - One raw s_barrier per window; manual s_waitcnt vmcnt(4)/vmcnt(12),
//     NEVER vmcnt(0) in steady state. Queue invariant entering window k:
//     [g2l(k):8, A(k,h0):4, A(k,h1):4].
//   - B-frag reads hoisted 8-deep before each 32-MFMA half (R5 pattern;
//     R8's JIT-reads regression avoided).
//   - XCD-banded block swizzle: each XCD owns a 4-j-tile band (N/P 2MB in
//     its L2), sweeps i.
//  Epilogue in squared-distance domain; atomicMax/Min on uint bits.
//
//  Dead-ends: R4 wave-private pipeline (184us); R6 unfused (182us); R7
//  reg-cliff dbuf (169us); R8 JIT B-reads (132us). R5 baseline = 96.5us.
// ---------------------------------------------------------------------------

#define NB 4096
#define DIM 1024
#define EPSF 1e-6f
#define D_EPS2 (1024.0f * 1e-6f * 1e-6f)

#define BM 128           // block tile (rows and cols)
#define BK 64            // k-tile -> 128 B LDS rows, 16 windows

typedef __bf16  bf16x8 __attribute__((ext_vector_type(8)));
typedef float   f32x4  __attribute__((ext_vector_type(4)));

__device__ __forceinline__ unsigned short f2bf(float x) {
    unsigned u = __float_as_uint(x);
    u += 0x7FFFu + ((u >> 16) & 1u);   // round-to-nearest-even
    return (unsigned short)(u >> 16);
}

// async 16B/lane global->LDS; lds base wave-uniform, data lands at base+lane*16
__device__ __forceinline__ void g2l16(const unsigned short* g, unsigned short* l) {
    __builtin_amdgcn_global_load_lds(
        (const __attribute__((address_space(1))) unsigned int*)g,
        (__attribute__((address_space(3))) unsigned int*)l, 16, 0, 0);
}

#define FENCE    asm volatile("" ::: "memory")
#define VM4      asm volatile("s_waitcnt vmcnt(4)" ::: "memory")
#define VM12     asm volatile("s_waitcnt vmcnt(12)" ::: "memory")
#define VM0      asm volatile("s_waitcnt vmcnt(0)" ::: "memory")
#define BARRIER  asm volatile("s_barrier" ::: "memory")

// stats layout (NB-float slots):
// 0: base_a[i]  1: cn[j]  2: cp[j]  3: d_ap  4: d_an_row
// 5: hard_n bits (sq)  6: hard_p bits (sq)

__global__ __launch_bounds__(256) void row_stats_kernel(
    const float* __restrict__ a, const float* __restrict__ p,
    const float* __restrict__ n,
    unsigned short* __restrict__ abf, unsigned short* __restrict__ pbf,
    unsigned short* __restrict__ nbf, float* __restrict__ stats)
{
    const int t    = threadIdx.x;
    const int wave = t >> 6, lane = t & 63;
    const int row  = blockIdx.x * 4 + wave;
    const size_t base = (size_t)row * DIM;

    const float4* a4 = (const float4*)(a + base);
    const float4* p4 = (const float4*)(p + base);
    const float4* n4 = (const float4*)(n + base);

    float v[8] = {0,0,0,0,0,0,0,0};   // sa qa sp qp sn qn dap2 dan2
#pragma unroll
    for (int c = 0; c < 4; c++) {
        const int idx = c * 64 + lane;
        const float4 va = a4[idx];
        const float4 vp = p4[idx];
        const float4 vn = n4[idx];
        const float fa[4] = {va.x, va.y, va.z, va.w};
        const float fp[4] = {vp.x, vp.y, vp.z, vp.w};
        const float fn[4] = {vn.x, vn.y, vn.z, vn.w};
#pragma unroll
        for (int e = 0; e < 4; e++) {
            v[0] += fa[e];           v[1] += fa[e] * fa[e];
            v[2] += fp[e];           v[3] += fp[e] * fp[e];
            v[4] += fn[e];           v[5] += fn[e] * fn[e];
            float dp = fa[e] - fp[e] + EPSF;  v[6] += dp * dp;
            float dn = fa[e] - fn[e] + EPSF;  v[7] += dn * dn;
        }
        ushort4 ba, bp, bn;
        ba.x = f2bf(fa[0]); ba.y = f2bf(fa[1]); ba.z = f2bf(fa[2]); ba.w = f2bf(fa[3]);
        bp.x = f2bf(fp[0]); bp.y = f2bf(fp[1]); bp.z = f2bf(fp[2]); bp.w = f2bf(fp[3]);
        bn.x = f2bf(fn[0]); bn.y = f2bf(fn[1]); bn.z = f2bf(fn[2]); bn.w = f2bf(fn[3]);
        ((ushort4*)(abf + base))[idx] = ba;
        ((ushort4*)(pbf + base))[idx] = bp;
        ((ushort4*)(nbf + base))[idx] = bn;
    }

#pragma unroll
    for (int m = 32; m >= 1; m >>= 1)
#pragma unroll
        for (int q = 0; q < 8; q++) v[q] += __shfl_xor(v[q], m);

    if (lane == 0) {
        stats[0 * NB + row] = v[1] + 2.0f * EPSF * v[0] + D_EPS2;  // base_a
        stats[1 * NB + row] = v[5] - 2.0f * EPSF * v[4];           // cn
        stats[2 * NB + row] = v[3] - 2.0f * EPSF * v[2];           // cp
        stats[3 * NB + row] = sqrtf(v[6]);                         // d_ap
        stats[4 * NB + row] = sqrtf(v[7]);                         // d_an_row
        ((unsigned*)stats)[5 * NB + row] = 0u;                     // hard_n
        ((unsigned*)stats)[6 * NB + row] = 0x7f800000u;            // hard_p
    }
}

// grid (32, 32). XCD-banded swizzle: id%8 = XCD owns j-band of 4 tiles.
__global__ __launch_bounds__(256, 2) void gemm_mask_kernel(
    const unsigned short* __restrict__ Abf,
    const unsigned short* __restrict__ Nbf,
    const unsigned short* __restrict__ Pbf,
    float* __restrict__ stats)
{
    const int id = blockIdx.y * 32 + blockIdx.x;
    const int xc = id & 7, rr = id >> 3;
    const int j0 = (xc * 4 + (rr & 3)) * BM;
    const int i0 = (rr >> 2) * BM;

    __shared__ unsigned short sN[2][BM * BK];   // 2 x 16 KB
    __shared__ unsigned short sP[2][BM * BK];   // 2 x 16 KB -> 64 KB total

    const int t    = threadIdx.x;
    const int wave = t >> 6, lane = t & 63;
    const int wm   = wave >> 1, wn = wave & 1;
    const int quad = lane >> 4, lrow = lane & 15;

    // ---- N/P staging: wave stages rows [wave*32,+32), 8 rows per g2l,
    // 4 g2l per mat per window. slot s = lane&7 of row r holds chunk s^(r&7).
    const int srow = lane >> 3;
    const int kch  = ((lane & 7) ^ srow) * 8;
    const unsigned short* gN = Nbf + (size_t)(j0 + wave * 32 + srow) * DIM + kch;
    const unsigned short* gP = Pbf + (size_t)(j0 + wave * 32 + srow) * DIM + kch;
    const int lb = (wave * 32) * BK;

    // ---- A direct global->VGPR: frag row = lane&15, k-subchunk = quad*8
    const unsigned short* gA = Abf + (size_t)(i0 + wm * 64 + lrow) * DIM + (quad << 3);

    // ---- B frag read: logical chunk c = half*4+quad, physical c^(lrow&7)
    const int rsw0 = ((0 + quad) ^ (lrow & 7)) * 8;
    const int rsw1 = ((4 + quad) ^ (lrow & 7)) * 8;
    const int pboff = (wn * 64 + lrow) * BK;

    bf16x8 afr0[4], afr1[4];
    f32x4 accN[4][4], accP[4][4];
#pragma unroll
    for (int im = 0; im < 4; im++)
#pragma unroll
        for (int jn = 0; jn < 4; jn++) {
            accN[im][jn] = (f32x4)(0.0f);
            accP[im][jn] = (f32x4)(0.0f);
        }

#define ISSUE_B(kw_, b_) do {                                                 \
    const unsigned short* _gn = gN + (size_t)(kw_) * BK;                      \
    const unsigned short* _gp = gP + (size_t)(kw_) * BK;                      \
    unsigned short* _ln = &sN[(b_)][lb];                                      \
    unsigned short* _lp = &sP[(b_)][lb];                                      \
    _Pragma("unroll")                                                         \
    for (int g = 0; g < 4; g++) {                                             \
        g2l16(_gn + (size_t)g * 8 * DIM, _ln + g * 8 * BK);                   \
        g2l16(_gp + (size_t)g * 8 * DIM, _lp + g * 8 * BK);                   \
    }                                                                         \
} while (0)

#define ISSUE_A(kw_, h_, arr_) do {                                           \
    const unsigned short* _ga = gA + (size_t)(kw_) * BK + (h_) * 32;          \
    _Pragma("unroll")                                                         \
    for (int im = 0; im < 4; im++)                                            \
        arr_[im] = *(const bf16x8*)(_ga + im * 16 * DIM);                     \
} while (0)

#define COMPUTE_HALF(b_, rsw_, arr_) do {                                     \
    bf16x8 bnfr[4], bpfr[4];                                                  \
    _Pragma("unroll")                                                         \
    for (int jn = 0; jn < 4; jn++) {                                          \
        bnfr[jn] = *(const bf16x8*)(&sN[(b_)][pboff + jn * 16 * BK + (rsw_)]);\
        bpfr[jn] = *(const bf16x8*)(&sP[(b_)][pboff + jn * 16 * BK + (rsw_)]);\
    }                                                                         \
    _Pragma("unroll")                                                         \
    for (int im = 0; im < 4; im++)                                            \
        _Pragma("unroll")                                                     \
        for (int jn = 0; jn < 4; jn++) {                                      \
            accN[im][jn] = __builtin_amdgcn_mfma_f32_16x16x32_bf16(           \
                arr_[im], bnfr[jn], accN[im][jn], 0, 0, 0);                   \
            accP[im][jn] = __builtin_amdgcn_mfma_f32_16x16x32_bf16(           \
                arr_[im], bpfr[jn], accP[im][jn], 0, 0, 0);                   \
        }                                                                     \
} while (0)

    // ---- prologue: queue = [g2l(0):8, A(0,h0):4, A(0,h1):4] ----
    ISSUE_B(0, 0);      FENCE;
    ISSUE_A(0, 0, afr0); FENCE;
    ISSUE_A(0, 1, afr1); FENCE;

    // ---- steady windows k = 0..14 ----
    for (int k = 0; k < 15; k++) {
        const int b = k & 1;
        VM4;                         // retire g2l(k) + A(k,h0); A(k,h1) left
        BARRIER;                     // all waves: buf[b] ready; prev reads done
        ISSUE_B(k + 1, b ^ 1); FENCE;
        COMPUTE_HALF(b, rsw0, afr0);
        ISSUE_A(k + 1, 0, afr0); FENCE;
        VM12;                        // retire A(k,h1) (covered by half0)
        COMPUTE_HALF(b, rsw1, afr1);
        ISSUE_A(k + 1, 1, afr1); FENCE;
    }
    // ---- peeled window 15: queue = [g2l(15):8, A(15,h0):4, A(15,h1):4] ----
    VM4;
    BARRIER;
    COMPUTE_HALF(1, rsw0, afr0);
    VM0;                             // retire A(15,h1) (covered by half0)
    COMPUTE_HALF(1, rsw1, afr1);

#undef COMPUTE_HALF
#undef ISSUE_A
#undef ISSUE_B

    // epilogue (SQUARED domain): sq = base_a[i] + c[j] - 2*dot
    const float* __restrict__ base_a = stats + 0 * NB;
    const float* __restrict__ cn_v   = stats + 1 * NB;
    const float* __restrict__ cp_v   = stats + 2 * NB;
    const float* __restrict__ d_ap   = stats + 3 * NB;
    const float* __restrict__ d_an   = stats + 4 * NB;
    unsigned* __restrict__ hard_n = ((unsigned*)stats) + 5 * NB;
    unsigned* __restrict__ hard_p = ((unsigned*)stats) + 6 * NB;

#pragma unroll
    for (int im = 0; im < 4; im++) {
#pragma unroll
        for (int r = 0; r < 4; r++) {
            const int gi = i0 + wm * 64 + im * 16 + quad * 4 + r;
            const float cutN = d_ap[gi];
            const float cutP = d_an[gi];
            const float cutN2 = cutN * cutN;
            const float cutP2 = cutP * cutP;
            const float bi    = base_a[gi];
            float bestN = 0.0f;
            float bestP = __uint_as_float(0x7f800000u);
#pragma unroll
            for (int jn = 0; jn < 4; jn++) {
                const int gj = j0 + wn * 64 + jn * 16 + lrow;
                const float sqN = fmaxf(bi + cn_v[gj] - 2.0f * accN[im][jn][r], 0.0f);
                const float sqP = fmaxf(bi + cp_v[gj] - 2.0f * accP[im][jn][r], 0.0f);
                if (sqN < cutN2 && sqN > bestN) bestN = sqN;
                if (sqP > cutP2 && sqP < bestP) bestP = sqP;
            }
#pragma unroll
            for (int m = 1; m < 16; m <<= 1) {
                bestN = fmaxf(bestN, __shfl_xor(bestN, m));
                bestP = fminf(bestP, __shfl_xor(bestP, m));
            }
            if (lrow == 0) {
                const unsigned bn_ = __float_as_uint(bestN);
                const unsigned bp_ = __float_as_uint(bestP);
                if (bn_ != 0u)          atomicMax(hard_n + gi, bn_);
                if (bp_ != 0x7f800000u) atomicMin(hard_p + gi, bp_);
            }
        }
    }
}

__global__ __launch_bounds__(1024) void finalize_kernel(
    const float* __restrict__ stats, float* __restrict__ out)
{
    const unsigned* hard_n = ((const unsigned*)stats) + 5 * NB;
    const unsigned* hard_p = ((const unsigned*)stats) + 6 * NB;
    const float*    d_ap   = stats + 3 * NB;
    const int t = threadIdx.x;
    const int wave = t >> 6, lane = t & 63;
    __shared__ float pn[16], pp[16];
    __shared__ float s_dan, s_dpp;

    float sn = 0.0f, sp = 0.0f;
    for (int i = t; i < NB; i += 1024) {
        sn += sqrtf(__uint_as_float(hard_n[i]));          // sq -> dist (0 -> 0)
        const unsigned hp = hard_p[i];
        if (hp != 0x7f800000u) sp += sqrtf(__uint_as_float(hp));
    }
#pragma unroll
    for (int m = 32; m >= 1; m >>= 1) {
        sn += __shfl_xor(sn, m);
        sp += __shfl_xor(sp, m);
    }
    if (lane == 0) { pn[wave] = sn; pp[wave] = sp; }
    __syncthreads();
    if (t == 0) {
        float an = 0.0f, ap = 0.0f;
#pragma unroll
        for (int w = 0; w < 16; w++) { an += pn[w]; ap += pp[w]; }
        s_dan = an / (float)NB;
        s_dpp = ap / (float)NB;
    }
    __syncthreads();
    const float dan = s_dan, dpp = s_dpp;

    float accv = 0.0f;
    for (int i = t; i < NB; i += 1024)
        accv += fmaxf(d_ap[i] - 0.5f * dpp - 0.5f * dan + 1.0f, 0.0f);
#pragma unroll
    for (int m = 32; m >= 1; m >>= 1) accv += __shfl_xor(accv, m);
    if (lane == 0) pn[wave] = accv;
    __syncthreads();
    if (t == 0) {
        float s = 0.0f;
#pragma unroll
        for (int w = 0; w < 16; w++) s += pn[w];
        out[0] = s / (float)NB;
    }
}

extern "C" void kernel_launch(void* const* d_in, const int* in_sizes, int n_in,
                              void* d_out, int out_size, void* d_ws, size_t ws_size,
                              hipStream_t stream) {
    const float* a = (const float*)d_in[0];
    const float* p = (const float*)d_in[1];
    const float* n = (const float*)d_in[2];
    float* out = (float*)d_out;

    // ws layout: abf | pbf | nbf | stats(7*NB floats)  => ~25.3 MB
    unsigned short* abf = (unsigned short*)d_ws;
    unsigned short* pbf = abf + (size_t)NB * DIM;
    unsigned short* nbf = pbf + (size_t)NB * DIM;
    float* stats = (float*)(nbf + (size_t)NB * DIM);

    row_stats_kernel<<<NB / 4, 256, 0, stream>>>(a, p, n, abf, pbf, nbf, stats);

    dim3 grid(NB / BM, NB / BM);
    gemm_mask_kernel<<<grid, 256, 0, stream>>>(abf, nbf, pbf, stats);

    finalize_kernel<<<1, 1024, 0, stream>>>(stats, out);
}